// Round 11
// baseline (219.427 us; speedup 1.0000x reference)
//
#include <hip/hip_runtime.h>
#include <math.h>

// Problem constants
#define BB 4
#define TT 1024
#define EE 1024
#define HH 16
#define DD 64
#define KDIM 1024
#define N_HS (4096 * 1024)     // hidden_states elems (also ctx)
#define N_W  (1024 * 1024)     // one weight matrix elems
#define NQKV (BB * HH * TT * DD)
#define LOG2E 1.44269504088896340736f

typedef _Float16 f16x8 __attribute__((ext_vector_type(8)));   // 4 VGPRs
typedef _Float16 f16x4 __attribute__((ext_vector_type(4)));   // 2 VGPRs
typedef _Float16 f16x2 __attribute__((ext_vector_type(2)));   // 1 VGPR
typedef float    f32x4 __attribute__((ext_vector_type(4)));

// fp32 -> fp16 bits, RTNE
__device__ __forceinline__ unsigned short f2h(float x) {
    _Float16 h = (_Float16)x;
    return __builtin_bit_cast(unsigned short, h);
}
// split x = hi + lo, both fp16
__device__ __forceinline__ void split_h(float x, unsigned short& hi, unsigned short& lo) {
    _Float16 h = (_Float16)x;
    hi = __builtin_bit_cast(unsigned short, h);
    lo = f2h(x - (float)h);
}

// packed fp32x2 -> fp16x2 (RTZ)
__device__ __forceinline__ f16x2 cvt_pk(float a, float b) {
    return __builtin_bit_cast(f16x2, __builtin_amdgcn_cvt_pkrtz(a, b));
}

// async global->LDS 16B copy
__device__ __forceinline__ void gload16(const void* g, void* l) {
    __builtin_amdgcn_global_load_lds(
        (const __attribute__((address_space(1))) void*)g,
        (__attribute__((address_space(3))) void*)l, 16, 0, 0);
}

__device__ __forceinline__ float mx3(float a, float b, float c) {
    return fmaxf(fmaxf(a, b), c);   // clang fuses to v_max3_f32
}

// ---------------------------------------------------------------------------
// Elementwise fp32 -> fp16 convert: hs + 4 weights, single plane each, PLUS
// mask zero-scan -> mflag.
// ws layout (ushort units):
//   [0]                      hs (N_HS)            (aliased as ctx_hi later)
//   [N_HS]                   wq, wk, wv, wo       (N_W each)
//   [N_HS+4*N_W]             q, k, v              (NQKV each)
//   [N_HS+4*N_W+3*NQKV]      ctx_lo               (N_HS)
//   [.. + N_HS]              vT                   (NQKV, [B,H,D,T])
//   [.. + NQKV]              mflag (int)
// ---------------------------------------------------------------------------
__global__ __launch_bounds__(256)
void split_kernel(const float* __restrict__ hs,
                  const float* __restrict__ Wq, const float* __restrict__ Wk,
                  const float* __restrict__ Wv, const float* __restrict__ Wo,
                  const float* __restrict__ mask, int* __restrict__ mflag,
                  unsigned short* __restrict__ ws)
{
    const int u = blockIdx.x * 256 + threadIdx.x;   // float4 id
    if (u < (N_HS / 4) + N_W) {                     // 2,097,152 convert slots
        const float* src;
        unsigned short* dst;
        if (u < (N_HS / 4)) {
            src = hs + (size_t)u * 4;
            dst = ws + (size_t)u * 4;
        } else {
            int v = u - N_HS / 4;
            int wsel = v >> 18;             // N_W/4 = 262144 float4 per weight
            int wo   = v & 0x3FFFF;
            const float* Wsrc = (wsel == 0) ? Wq : (wsel == 1) ? Wk : (wsel == 2) ? Wv : Wo;
            src = Wsrc + (size_t)wo * 4;
            dst = ws + (size_t)N_HS + (size_t)wsel * N_W + (size_t)wo * 4;
        }
        float4 x = *(const float4*)src;
        ushort4 h4;
        h4.x = f2h(x.x); h4.y = f2h(x.y); h4.z = f2h(x.z); h4.w = f2h(x.w);
        *(ushort4*)dst = h4;
    } else {
        // mask scan: 1,048,576 float4 (B*T*T = 16 MB)
        int v = u - ((N_HS / 4) + N_W);
        float4 x = *(const float4*)(mask + (size_t)v * 4);
        bool nz = (x.x != 0.f) || (x.y != 0.f) || (x.z != 0.f) || (x.w != 0.f);
        if (__any(nz) && (threadIdx.x & 63) == 0)
            atomicOr(mflag, 1);
    }
}

// ---------------------------------------------------------------------------
// QKV projection, single-fp16 MFMA, BK=32 DOUBLE-BUFFERED (attn's schedule:
// stage next K-step during current compute, one barrier per step -- no
// vmcnt(0) drain between stage and compute). LDS 32KB.
// Q additionally scaled by log2e so the attention softmax uses exp2.
// ---------------------------------------------------------------------------
__global__ __launch_bounds__(256)
void qkv_kernel(const unsigned short* __restrict__ hsp,
                const unsigned short* __restrict__ wqp,
                const float* __restrict__ bq, const float* __restrict__ bk,
                const float* __restrict__ bv,
                unsigned short* __restrict__ qkvb)
{
    __shared__ unsigned short Ah[2][128 * 32], Bh[2][128 * 32];   // 32KB

    const int widx  = blockIdx.x >> 3;
    const int nbase = (blockIdx.x & 7) * 128;
    const int mbase = blockIdx.y * 128;
    const unsigned short* Wp = wqp + (size_t)widx * N_W;
    const float* bias = (widx == 0) ? bq : (widx == 1) ? bk : bv;
    unsigned short* dst = qkvb + (size_t)widx * NQKV;
    const float scale = (widx == 0) ? 0.125f * LOG2E : 1.0f;   // D^-0.5 * log2e

    const int tid  = threadIdx.x;
    const int w    = tid >> 6;
    const int lane = tid & 63;
    const int quad = lane >> 4;
    const int l16  = lane & 15;
    const int wm   = (w >> 1) * 64;
    const int wn   = (w & 1) * 64;

    f32x4 acc[4][4];
#pragma unroll
    for (int i = 0; i < 4; i++)
#pragma unroll
        for (int j = 0; j < 4; j++) acc[i][j] = (f32x4)0.f;

    // prologue: stage kt=0 into buf 0
#pragma unroll
    for (int i = 0; i < 2; i++) {
        int u = tid + i * 256;              // 512 chunks/plane
        int r = u >> 2, c = u & 3;
        int q = c ^ ((r >> 1) & 3);
        gload16(hsp + (size_t)(mbase + r) * KDIM + q * 8, &Ah[0][u * 8]);
        gload16(Wp  + (size_t)(nbase + r) * KDIM + q * 8, &Bh[0][u * 8]);
    }
    __syncthreads();

#pragma unroll 2
    for (int step = 0; step < 32; ++step) {
        const int cur = step & 1;           // compile-time per unrolled copy
        const int kt  = step * 32;

        // stage NEXT K-step into the other buffer; overlaps compute below
        if (step < 31) {
#pragma unroll
            for (int i = 0; i < 2; i++) {
                int u = tid + i * 256;
                int r = u >> 2, c = u & 3;
                int q = c ^ ((r >> 1) & 3);
                gload16(hsp + (size_t)(mbase + r) * KDIM + kt + 32 + q * 8, &Ah[cur ^ 1][u * 8]);
                gload16(Wp  + (size_t)(nbase + r) * KDIM + kt + 32 + q * 8, &Bh[cur ^ 1][u * 8]);
            }
        }

        f16x8 af[4], bfr[4];
#pragma unroll
        for (int i = 0; i < 4; i++) {
            int r = wm + i * 16 + l16;
            af[i] = *(const f16x8*)&Ah[cur][(r * 4 + (quad ^ ((r >> 1) & 3))) * 8];
        }
#pragma unroll
        for (int j = 0; j < 4; j++) {
            int r = wn + j * 16 + l16;
            bfr[j] = *(const f16x8*)&Bh[cur][(r * 4 + (quad ^ ((r >> 1) & 3))) * 8];
        }
#pragma unroll
        for (int i = 0; i < 4; i++)
#pragma unroll
            for (int j = 0; j < 4; j++)
                acc[i][j] = __builtin_amdgcn_mfma_f32_16x16x32_f16(af[i], bfr[j], acc[i][j], 0, 0, 0);

        // one barrier per step: drains the NEXT-step DMA after a full
        // compute phase, and closes the read window on buf cur.
        __syncthreads();
    }

    // epilogue: +bias, *scale, fp16, scatter to [B,H,T,D]
#pragma unroll
    for (int j = 0; j < 4; j++) {
        int n = nbase + wn + j * 16 + l16;
        int h = n >> 6, d = n & 63;
        float bj = bias[n];
#pragma unroll
        for (int i = 0; i < 4; i++)
#pragma unroll
            for (int rr = 0; rr < 4; rr++) {
                int m = mbase + wm + i * 16 + quad * 4 + rr;
                int b = m >> 10, t = m & 1023;
                dst[(((size_t)(b * HH + h) * TT + t) * DD + d)] =
                    f2h((acc[i][j][rr] + bj) * scale);
            }
    }
}

// ---------------------------------------------------------------------------
// V transpose: [B,H,T,D] -> [B,H,D,T] fp16, via LDS tile.
// ---------------------------------------------------------------------------
__global__ __launch_bounds__(256)
void vtrans_kernel(const unsigned short* __restrict__ vp,
                   unsigned short* __restrict__ vtp)
{
    __shared__ unsigned short Ts[64 * 72];
    const int bh = blockIdx.y;
    const int t0 = blockIdx.x * 64;
    const unsigned short* src = vp  + (size_t)bh * TT * DD + (size_t)t0 * DD;
    unsigned short*       dst = vtp + (size_t)bh * DD * TT + t0;
    const int tid = threadIdx.x;

#pragma unroll
    for (int i = 0; i < 2; i++) {
        int id = tid + i * 256;           // 512 uint4: row r (token), chunk c (8 d)
        int r = id >> 3, c = id & 7;
        *(uint4*)&Ts[r * 72 + c * 8] = *(const uint4*)(src + (size_t)r * DD + c * 8);
    }
    __syncthreads();
#pragma unroll
    for (int i = 0; i < 2; i++) {
        int id = tid + i * 256;           // 512 uint4: row d, chunk c (8 tokens)
        int d = id >> 3, c = id & 7;
        unsigned short tmp[8];
#pragma unroll
        for (int j = 0; j < 8; j++) tmp[j] = Ts[(c * 8 + j) * 72 + d];
        uint4 o;
        o.x = (unsigned int)tmp[0] | ((unsigned int)tmp[1] << 16);
        o.y = (unsigned int)tmp[2] | ((unsigned int)tmp[3] << 16);
        o.z = (unsigned int)tmp[4] | ((unsigned int)tmp[5] << 16);
        o.w = (unsigned int)tmp[6] | ((unsigned int)tmp[7] << 16);
        *(uint4*)(dst + (size_t)d * TT + c * 8) = o;
    }
}

// ---------------------------------------------------------------------------
// Out projection, 2-term fp16, BK=32 DOUBLE-BUFFERED (same schedule as qkv).
// LDS 32KB.
// ---------------------------------------------------------------------------
__global__ __launch_bounds__(256)
void outproj_kernel(const unsigned short* __restrict__ ctxh,
                    const unsigned short* __restrict__ ctxl,
                    const unsigned short* __restrict__ wop,
                    const float* __restrict__ bo, float* __restrict__ out)
{
    __shared__ unsigned short Ach[2][64 * 32], Acl[2][64 * 32], Bh[2][128 * 32]; // 32KB

    const int nbase = blockIdx.x * 128;
    const int mbase = blockIdx.y * 64;

    const int tid  = threadIdx.x;
    const int w    = tid >> 6;
    const int lane = tid & 63;
    const int quad = lane >> 4;
    const int l16  = lane & 15;
    const int wm   = (w >> 1) * 32;
    const int wn   = (w & 1) * 64;

    f32x4 acc[2][4];
#pragma unroll
    for (int i = 0; i < 2; i++)
#pragma unroll
        for (int j = 0; j < 4; j++) acc[i][j] = (f32x4)0.f;

    // prologue: stage kt=0 into buf 0
    {
        int r = tid >> 2, c = tid & 3;
        int q = c ^ ((r >> 1) & 3);
        size_t ga = (size_t)(mbase + r) * KDIM + q * 8;
        gload16(ctxh + ga, &Ach[0][tid * 8]);
        gload16(ctxl + ga, &Acl[0][tid * 8]);
    }
#pragma unroll
    for (int i = 0; i < 2; i++) {
        int u = tid + i * 256;
        int r = u >> 2, c = u & 3;
        int q = c ^ ((r >> 1) & 3);
        gload16(wop + (size_t)(nbase + r) * KDIM + q * 8, &Bh[0][u * 8]);
    }
    __syncthreads();

#pragma unroll 2
    for (int step = 0; step < 32; ++step) {
        const int cur = step & 1;
        const int kt  = step * 32;

        // stage NEXT K-step into the other buffer
        if (step < 31) {
            {
                int r = tid >> 2, c = tid & 3;
                int q = c ^ ((r >> 1) & 3);
                size_t ga = (size_t)(mbase + r) * KDIM + kt + 32 + q * 8;
                gload16(ctxh + ga, &Ach[cur ^ 1][tid * 8]);
                gload16(ctxl + ga, &Acl[cur ^ 1][tid * 8]);
            }
#pragma unroll
            for (int i = 0; i < 2; i++) {
                int u = tid + i * 256;
                int r = u >> 2, c = u & 3;
                int q = c ^ ((r >> 1) & 3);
                gload16(wop + (size_t)(nbase + r) * KDIM + kt + 32 + q * 8, &Bh[cur ^ 1][u * 8]);
            }
        }

        f16x8 ah[2], al[2], bfr[4];
#pragma unroll
        for (int i = 0; i < 2; i++) {
            int r = wm + i * 16 + l16;
            int slot = (r * 4 + (quad ^ ((r >> 1) & 3))) * 8;
            ah[i] = *(const f16x8*)&Ach[cur][slot];
            al[i] = *(const f16x8*)&Acl[cur][slot];
        }
#pragma unroll
        for (int j = 0; j < 4; j++) {
            int r = wn + j * 16 + l16;
            bfr[j] = *(const f16x8*)&Bh[cur][(r * 4 + (quad ^ ((r >> 1) & 3))) * 8];
        }
#pragma unroll
        for (int i = 0; i < 2; i++)
#pragma unroll
            for (int j = 0; j < 4; j++) {
                acc[i][j] = __builtin_amdgcn_mfma_f32_16x16x32_f16(ah[i], bfr[j], acc[i][j], 0, 0, 0);
                acc[i][j] = __builtin_amdgcn_mfma_f32_16x16x32_f16(al[i], bfr[j], acc[i][j], 0, 0, 0);
            }

        __syncthreads();
    }

#pragma unroll
    for (int j = 0; j < 4; j++) {
        int n = nbase + wn + j * 16 + l16;
        float bj = bo[n];
#pragma unroll
        for (int i = 0; i < 2; i++)
#pragma unroll
            for (int rr = 0; rr < 4; rr++) {
                int m = mbase + wm + i * 16 + quad * 4 + rr;
                out[(size_t)m * EE + n] = acc[i][j][rr] + bj;
            }
    }
}

// ---------------------------------------------------------------------------
// MFMA flash attention, fp16, swapped-operand layout, BM=128 (4 waves x 32
// query rows), XCD-bijective block swizzle. Unchanged from R10.
// ---------------------------------------------------------------------------
__global__ __launch_bounds__(256)
void attn_kernel(const unsigned short* __restrict__ qp_, const unsigned short* __restrict__ kp_,
                 const unsigned short* __restrict__ vtp_,
                 const float* __restrict__ mask, const int* __restrict__ mflag,
                 unsigned short* __restrict__ ctxh, unsigned short* __restrict__ ctxl)
{
    __shared__ unsigned short Ks[2][64 * 64];  // rows kv, cols d; chunk-XOR swizzled
    __shared__ unsigned short Vt[2][64 * 64];  // rows d, cols kv; chunk-XOR swizzled

    const int orig = blockIdx.x;
    const int wgid = (orig & 7) * 64 + (orig >> 3);
    const int bh = wgid >> 3;
    const int b  = bh >> 4;
    const int h  = bh & 15;
    const int m0 = (wgid & 7) * 128;
    const size_t hoff = (size_t)bh * TT * DD;
    const unsigned short* qhp = qp_ + hoff;
    const unsigned short* khp = kp_ + hoff;
    const unsigned short* vtp = vtp_ + hoff;   // [D][T] for this bh
    const float* mb = mask + (size_t)b * TT * TT;  // [m][kv] (general path only)

    const int tid  = threadIdx.x;
    const int w    = tid >> 6;
    const int lane = tid & 63;
    const int quad = lane >> 4;
    const int l16  = lane & 15;
    const int mw   = m0 + w * 32;              // wave's 32-row base

    const int usemask = mflag[0];              // wave-uniform scalar

    // ---- loop-invariant LDS element offsets (runtime part only) ----
    const int lm7 = l16 & 7;
    const int x0  = l16 * 64 + ((quad)     ^ lm7) * 8;
    const int x1  = l16 * 64 + ((4 + quad) ^ lm7) * 8;
    const int qh  = quad >> 1, ql = quad & 1;
    int yy[4];
#pragma unroll
    for (int t = 0; t < 4; t++)
        yy[t] = l16 * 64 + ((2 * t + qh) ^ lm7) * 8 + ql * 4;
    const unsigned short* Ksf = &Ks[0][0];
    const unsigned short* Vtf = &Vt[0][0];

    // Q fragments: 2 row-groups, resident whole kernel
    f16x8 qf[2][2];
#pragma unroll
    for (int g = 0; g < 2; g++)
#pragma unroll
        for (int s = 0; s < 2; s++)
            qf[g][s] = *(const f16x8*)(qhp + (size_t)(mw + g * 16 + l16) * DD + s * 32 + quad * 8);

    f32x4 o2[2][4];              // O^T frags per group
#pragma unroll
    for (int g = 0; g < 2; g++)
#pragma unroll
        for (int u = 0; u < 4; u++) o2[g][u] = (f32x4)0.f;
    f32x4 lv[2];
    lv[0] = (f32x4)0.f; lv[1] = (f32x4)0.f;
    const f32x4 zc = (f32x4)0.f;
    f16x4 onesv;
    onesv[0] = (_Float16)1.f; onesv[1] = (_Float16)1.f;
    onesv[2] = (_Float16)1.f; onesv[3] = (_Float16)1.f;
    float m_i[2] = { -INFINITY, -INFINITY };

    // prologue: stage tile 0 (source-side XOR swizzle, linear LDS dest)
#pragma unroll
    for (int i = 0; i < 2; i++) {
        int u = tid + i * 256;
        int r = u >> 3, cp = u & 7;
        int c = cp ^ (r & 7);
        gload16(khp + (size_t)r * DD + c * 8, &Ks[0][u * 8]);
        gload16(vtp + (size_t)r * TT + c * 8, &Vt[0][u * 8]);
    }
    __syncthreads();

#pragma unroll 2
    for (int it = 0; it < 16; ++it) {
        const int n0  = it * 64;
        const int cur = it & 1;              // compile-time per unrolled copy

        // stage NEXT K/V tile into the other buffer; overlaps all compute below
        if (it < 15) {
#pragma unroll
            for (int i = 0; i < 2; i++) {
                int u = tid + i * 256;
                int r = u >> 3, cp = u & 7;
                int c = cp ^ (r & 7);
                gload16(khp + (size_t)(n0 + 64 + r) * DD + c * 8, &Ks[cur ^ 1][u * 8]);
                gload16(vtp + (size_t)r * TT + n0 + 64 + c * 8,   &Vt[cur ^ 1][u * 8]);
            }
        }

        // S^T init: zero C (fast path) or strided mask reads (general path)
        f32x4 st[2][4];
        if (usemask) {
#pragma unroll
            for (int g = 0; g < 2; g++)
#pragma unroll
                for (int t = 0; t < 4; t++)
#pragma unroll
                    for (int r = 0; r < 4; r++)
                        st[g][t][r] = mb[(size_t)(mw + g * 16 + l16) * TT + n0 + 16 * t + quad * 4 + r] * LOG2E;
        } else {
#pragma unroll
            for (int g = 0; g < 2; g++)
#pragma unroll
                for (int t = 0; t < 4; t++) st[g][t] = zc;
        }

        // S^T = K.Q^T + init; each kf feeds BOTH row-groups
        __builtin_amdgcn_s_setprio(1);
#pragma unroll
        for (int t = 0; t < 4; t++) {
            const f16x8 kf = *(const f16x8*)(Ksf + cur * 4096 + x0 + t * 1024);
            st[0][t] = __builtin_amdgcn_mfma_f32_16x16x32_f16(kf, qf[0][0], st[0][t], 0, 0, 0);
            st[1][t] = __builtin_amdgcn_mfma_f32_16x16x32_f16(kf, qf[1][0], st[1][t], 0, 0, 0);
        }
#pragma unroll
        for (int t = 0; t < 4; t++) {
            const f16x8 kf = *(const f16x8*)(Ksf + cur * 4096 + x1 + t * 1024);
            st[0][t] = __builtin_amdgcn_mfma_f32_16x16x32_f16(kf, qf[0][1], st[0][t], 0, 0, 0);
            st[1][t] = __builtin_amdgcn_mfma_f32_16x16x32_f16(kf, qf[1][1], st[1][t], 0, 0, 0);
        }
        __builtin_amdgcn_s_setprio(0);

        // online softmax per row-group
        f16x4 pb[2][4];
#pragma unroll
        for (int g = 0; g < 2; g++) {
            float g0 = mx3(st[g][0][0], st[g][0][1], st[g][0][2]);
            float g1 = mx3(st[g][0][3], st[g][1][0], st[g][1][1]);
            float g2 = mx3(st[g][1][2], st[g][1][3], st[g][2][0]);
            float g3 = mx3(st[g][2][1], st[g][2][2], st[g][2][3]);
            float g4 = mx3(st[g][3][0], st[g][3][1], st[g][3][2]);
            float rm = fmaxf(mx3(g0, g1, g2), mx3(g3, g4, st[g][3][3]));
            rm = fmaxf(rm, __shfl_xor(rm, 16));
            rm = fmaxf(rm, __shfl_xor(rm, 32));

            // defer-max (T13)
            if (__any(rm > m_i[g] + 8.f)) {
                float mn    = fmaxf(m_i[g], rm);
                float alpha = exp2f(m_i[g] - mn);
                m_i[g] = mn;
#pragma unroll
                for (int rr = 0; rr < 4; rr++) lv[g][rr] *= alpha;
#pragma unroll
                for (int u = 0; u < 4; u++)
#pragma unroll
                    for (int rr = 0; rr < 4; rr++) o2[g][u][rr] *= alpha;
            }

            // P = exp2(S - m), packed fp16 (B-frag of 16x16x16 directly)
#pragma unroll
            for (int t = 0; t < 4; t++) {
                float p0 = exp2f(st[g][t][0] - m_i[g]);
                float p1 = exp2f(st[g][t][1] - m_i[g]);
                float p2 = exp2f(st[g][t][2] - m_i[g]);
                float p3 = exp2f(st[g][t][3] - m_i[g]);
                f16x2 plo = cvt_pk(p0, p1);
                f16x2 phi = cvt_pk(p2, p3);
                f16x4 pv;
                pv[0] = plo[0]; pv[1] = plo[1]; pv[2] = phi[0]; pv[3] = phi[1];
                pb[g][t] = pv;
            }
        }

        // l += sum_k P (ones-MFMA); O^T += V^T.P^T; each vv feeds BOTH groups
        __builtin_amdgcn_s_setprio(1);
#pragma unroll
        for (int t = 0; t < 4; t++) {
            lv[0] = __builtin_amdgcn_mfma_f32_16x16x16f16(onesv, pb[0][t], lv[0], 0, 0, 0);
            lv[1] = __builtin_amdgcn_mfma_f32_16x16x16f16(onesv, pb[1][t], lv[1], 0, 0, 0);
        }
#pragma unroll
        for (int u = 0; u < 4; u++) {
#pragma unroll
            for (int t = 0; t < 4; t++) {
                const f16x4 vv = *(const f16x4*)(Vtf + cur * 4096 + yy[t] + u * 1024);
                o2[0][u] = __builtin_amdgcn_mfma_f32_16x16x16f16(vv, pb[0][t], o2[0][u], 0, 0, 0);
                o2[1][u] = __builtin_amdgcn_mfma_f32_16x16x16f16(vv, pb[1][t], o2[1][u], 0, 0, 0);
            }
        }
        __builtin_amdgcn_s_setprio(0);

        // single barrier per iteration
        __syncthreads();
    }

    // epilogue: normalize, split fp16 hi/lo ctx planes [B,T,E]
#pragma unroll
    for (int g = 0; g < 2; g++) {
        float inv = 1.0f / lv[g][0];
        int m = mw + g * 16 + l16;
#pragma unroll
        for (int u = 0; u < 4; u++)
#pragma unroll
            for (int rr = 0; rr < 4; rr++) {
                float val = o2[g][u][rr] * inv;
                unsigned short hi, lo;
                split_h(val, hi, lo);
                size_t off = ((size_t)(b * TT + m)) * EE + h * DD + u * 16 + quad * 4 + rr;
                ctxh[off] = hi;
                ctxl[off] = lo;
            }
    }
}

// ---------------------------------------------------------------------------
extern "C" void kernel_launch(void* const* d_in, const int* in_sizes, int n_in,
                              void* d_out, int out_size, void* d_ws, size_t ws_size,
                              hipStream_t stream)
{
    const float* hs   = (const float*)d_in[0];
    const float* mask = (const float*)d_in[1];
    const float* Wq   = (const float*)d_in[2];
    const float* bq   = (const float*)d_in[3];
    const float* Wk   = (const float*)d_in[4];
    const float* bk   = (const float*)d_in[5];
    const float* Wv   = (const float*)d_in[6];
    const float* bv   = (const float*)d_in[7];
    const float* Wo   = (const float*)d_in[8];
    const float* bo   = (const float*)d_in[9];
    float* out = (float*)d_out;

    unsigned short* ws   = (unsigned short*)d_ws;
    unsigned short* hsp  = ws;                                  // fp16 hs (-> ctx_hi)
    unsigned short* wqp  = ws + (size_t)N_HS;                   // wq,wk,wv,wo
    unsigned short* wop  = wqp + 3 * (size_t)N_W;
    unsigned short* qkvb = wqp + 4 * (size_t)N_W;               // q,k,v planes
    unsigned short* qp   = qkvb;
    unsigned short* kp   = qp + (size_t)NQKV;
    unsigned short* vp   = kp + (size_t)NQKV;
    unsigned short* ctxh = ws;                                  // alias hs (dead after qkv)
    unsigned short* ctxl = qkvb + 3 * (size_t)NQKV;
    unsigned short* vtp  = ctxl + (size_t)N_HS;                 // V^T [B,H,D,T]
    int*            mflag = (int*)(vtp + (size_t)NQKV);         // zero-mask flag

    (void)hipMemsetAsync(mflag, 0, sizeof(int), stream);
    split_kernel<<<12288, 256, 0, stream>>>(hs, Wq, Wk, Wv, Wo, mask, mflag, ws);
    qkv_kernel<<<dim3(24, 32), 256, 0, stream>>>(hsp, wqp, bq, bk, bv, qkvb);
    vtrans_kernel<<<dim3(TT / 64, BB * HH), 256, 0, stream>>>(vp, vtp);
    attn_kernel<<<512, 256, 0, stream>>>(qp, kp, vtp, mask, mflag, ctxh, ctxl);
    outproj_kernel<<<dim3(8, 64), 256, 0, stream>>>(ctxh, ctxl, wop, bo, out);
}

// Round 12
// 209.204 us; speedup vs baseline: 1.0489x; 1.0489x over previous
//
#include <hip/hip_runtime.h>
#include <math.h>

// Problem constants
#define BB 4
#define TT 1024
#define EE 1024
#define HH 16
#define DD 64
#define KDIM 1024
#define N_HS (4096 * 1024)     // hidden_states elems (also ctx)
#define N_W  (1024 * 1024)     // one weight matrix elems
#define NQKV (BB * HH * TT * DD)
#define LOG2E 1.44269504088896340736f

typedef _Float16 f16x8 __attribute__((ext_vector_type(8)));   // 4 VGPRs
typedef _Float16 f16x4 __attribute__((ext_vector_type(4)));   // 2 VGPRs
typedef _Float16 f16x2 __attribute__((ext_vector_type(2)));   // 1 VGPR
typedef float    f32x4 __attribute__((ext_vector_type(4)));

// fp32 -> fp16 bits, RTNE
__device__ __forceinline__ unsigned short f2h(float x) {
    _Float16 h = (_Float16)x;
    return __builtin_bit_cast(unsigned short, h);
}

// packed fp32x2 -> fp16x2 (RTZ)
__device__ __forceinline__ f16x2 cvt_pk(float a, float b) {
    return __builtin_bit_cast(f16x2, __builtin_amdgcn_cvt_pkrtz(a, b));
}

// async global->LDS 16B copy
__device__ __forceinline__ void gload16(const void* g, void* l) {
    __builtin_amdgcn_global_load_lds(
        (const __attribute__((address_space(1))) void*)g,
        (__attribute__((address_space(3))) void*)l, 16, 0, 0);
}

__device__ __forceinline__ float mx3(float a, float b, float c) {
    return fmaxf(fmaxf(a, b), c);   // clang fuses to v_max3_f32
}

// ---------------------------------------------------------------------------
// Elementwise fp32 -> fp16 convert: hs + 4 weights, single plane each, PLUS
// mask zero-scan -> mflag.
// ws layout (ushort units):
//   [0]                      hs (N_HS)            (aliased as ctx later)
//   [N_HS]                   wq, wk, wv, wo       (N_W each)
//   [N_HS+4*N_W]             q, k, v              (NQKV each)
//   [N_HS+4*N_W+3*NQKV]      (spare)              (N_HS)
//   [.. + N_HS]              vT                   (NQKV, [B,H,D,T])
//   [.. + NQKV]              mflag (int)
// ---------------------------------------------------------------------------
__global__ __launch_bounds__(256)
void split_kernel(const float* __restrict__ hs,
                  const float* __restrict__ Wq, const float* __restrict__ Wk,
                  const float* __restrict__ Wv, const float* __restrict__ Wo,
                  const float* __restrict__ mask, int* __restrict__ mflag,
                  unsigned short* __restrict__ ws)
{
    const int u = blockIdx.x * 256 + threadIdx.x;   // float4 id
    if (u < (N_HS / 4) + N_W) {                     // 2,097,152 convert slots
        const float* src;
        unsigned short* dst;
        if (u < (N_HS / 4)) {
            src = hs + (size_t)u * 4;
            dst = ws + (size_t)u * 4;
        } else {
            int v = u - N_HS / 4;
            int wsel = v >> 18;             // N_W/4 = 262144 float4 per weight
            int wo   = v & 0x3FFFF;
            const float* Wsrc = (wsel == 0) ? Wq : (wsel == 1) ? Wk : (wsel == 2) ? Wv : Wo;
            src = Wsrc + (size_t)wo * 4;
            dst = ws + (size_t)N_HS + (size_t)wsel * N_W + (size_t)wo * 4;
        }
        float4 x = *(const float4*)src;
        ushort4 h4;
        h4.x = f2h(x.x); h4.y = f2h(x.y); h4.z = f2h(x.z); h4.w = f2h(x.w);
        *(ushort4*)dst = h4;
    } else {
        // mask scan: 1,048,576 float4 (B*T*T = 16 MB)
        int v = u - ((N_HS / 4) + N_W);
        float4 x = *(const float4*)(mask + (size_t)v * 4);
        bool nz = (x.x != 0.f) || (x.y != 0.f) || (x.z != 0.f) || (x.w != 0.f);
        if (__any(nz) && (threadIdx.x & 63) == 0)
            atomicOr(mflag, 1);
    }
}

// ---------------------------------------------------------------------------
// QKV projection, single-fp16 MFMA, BK=64 single-buffered (R9 structure --
// the double-buffer variant measured neutral-to-negative, m99/m100 style).
// Q additionally scaled by log2e so the attention softmax uses exp2.
// ---------------------------------------------------------------------------
__global__ __launch_bounds__(256)
void qkv_kernel(const unsigned short* __restrict__ hsp,
                const unsigned short* __restrict__ wqp,
                const float* __restrict__ bq, const float* __restrict__ bk,
                const float* __restrict__ bv,
                unsigned short* __restrict__ qkvb)
{
    __shared__ unsigned short Ah[128 * 64], Bh[128 * 64];   // 32KB total

    const int widx  = blockIdx.x >> 3;
    const int nbase = (blockIdx.x & 7) * 128;
    const int mbase = blockIdx.y * 128;
    const unsigned short* Wp = wqp + (size_t)widx * N_W;
    const float* bias = (widx == 0) ? bq : (widx == 1) ? bk : bv;
    unsigned short* dst = qkvb + (size_t)widx * NQKV;
    const float scale = (widx == 0) ? 0.125f * LOG2E : 1.0f;   // D^-0.5 * log2e

    const int tid  = threadIdx.x;
    const int w    = tid >> 6;
    const int lane = tid & 63;
    const int quad = lane >> 4;
    const int l16  = lane & 15;
    const int wm   = (w >> 1) * 64;
    const int wn   = (w & 1) * 64;

    f32x4 acc[4][4];
#pragma unroll
    for (int i = 0; i < 4; i++)
#pragma unroll
        for (int j = 0; j < 4; j++) acc[i][j] = (f32x4)0.f;

#pragma unroll 1
    for (int kt = 0; kt < KDIM; kt += 64) {
        __syncthreads();
#pragma unroll
        for (int i = 0; i < 4; i++) {
            int u = tid + i * 256;              // 16B chunk id, 1024/plane
            int r = u >> 3, cp = u & 7;
            int c = cp ^ (r & 7);
            gload16(hsp + (size_t)(mbase + r) * KDIM + kt + c * 8, &Ah[u * 8]);
            gload16(Wp  + (size_t)(nbase + r) * KDIM + kt + c * 8, &Bh[u * 8]);
        }
        __syncthreads();

#pragma unroll
        for (int ks = 0; ks < 2; ks++) {
            f16x8 af[4], bfr[4];
#pragma unroll
            for (int i = 0; i < 4; i++) {
                int r = wm + i * 16 + l16;
                af[i] = *(const f16x8*)&Ah[(r * 8 + ((ks * 4 + quad) ^ (r & 7))) * 8];
            }
#pragma unroll
            for (int j = 0; j < 4; j++) {
                int r = wn + j * 16 + l16;
                bfr[j] = *(const f16x8*)&Bh[(r * 8 + ((ks * 4 + quad) ^ (r & 7))) * 8];
            }
#pragma unroll
            for (int i = 0; i < 4; i++)
#pragma unroll
                for (int j = 0; j < 4; j++)
                    acc[i][j] = __builtin_amdgcn_mfma_f32_16x16x32_f16(af[i], bfr[j], acc[i][j], 0, 0, 0);
        }
    }

    // epilogue: +bias, *scale, fp16, scatter to [B,H,T,D]
#pragma unroll
    for (int j = 0; j < 4; j++) {
        int n = nbase + wn + j * 16 + l16;
        int h = n >> 6, d = n & 63;
        float bj = bias[n];
#pragma unroll
        for (int i = 0; i < 4; i++)
#pragma unroll
            for (int rr = 0; rr < 4; rr++) {
                int m = mbase + wm + i * 16 + quad * 4 + rr;
                int b = m >> 10, t = m & 1023;
                dst[(((size_t)(b * HH + h) * TT + t) * DD + d)] =
                    f2h((acc[i][j][rr] + bj) * scale);
            }
    }
}

// ---------------------------------------------------------------------------
// V transpose: [B,H,T,D] -> [B,H,D,T] fp16, via LDS tile.
// ---------------------------------------------------------------------------
__global__ __launch_bounds__(256)
void vtrans_kernel(const unsigned short* __restrict__ vp,
                   unsigned short* __restrict__ vtp)
{
    __shared__ unsigned short Ts[64 * 72];
    const int bh = blockIdx.y;
    const int t0 = blockIdx.x * 64;
    const unsigned short* src = vp  + (size_t)bh * TT * DD + (size_t)t0 * DD;
    unsigned short*       dst = vtp + (size_t)bh * DD * TT + t0;
    const int tid = threadIdx.x;

#pragma unroll
    for (int i = 0; i < 2; i++) {
        int id = tid + i * 256;           // 512 uint4: row r (token), chunk c (8 d)
        int r = id >> 3, c = id & 7;
        *(uint4*)&Ts[r * 72 + c * 8] = *(const uint4*)(src + (size_t)r * DD + c * 8);
    }
    __syncthreads();
#pragma unroll
    for (int i = 0; i < 2; i++) {
        int id = tid + i * 256;           // 512 uint4: row d, chunk c (8 tokens)
        int d = id >> 3, c = id & 7;
        unsigned short tmp[8];
#pragma unroll
        for (int j = 0; j < 8; j++) tmp[j] = Ts[(c * 8 + j) * 72 + d];
        uint4 o;
        o.x = (unsigned int)tmp[0] | ((unsigned int)tmp[1] << 16);
        o.y = (unsigned int)tmp[2] | ((unsigned int)tmp[3] << 16);
        o.z = (unsigned int)tmp[4] | ((unsigned int)tmp[5] << 16);
        o.w = (unsigned int)tmp[6] | ((unsigned int)tmp[7] << 16);
        *(uint4*)(dst + (size_t)d * TT + c * 8) = o;
    }
}

// ---------------------------------------------------------------------------
// Out projection, SINGLE-term fp16, BK=64. ctx is one fp16 plane; Wo is
// already single fp16 (same truncation magnitude, accepted since R0), so the
// added error is RMS-comparable to the existing absmax floor.
// ---------------------------------------------------------------------------
__global__ __launch_bounds__(256)
void outproj_kernel(const unsigned short* __restrict__ ctxh,
                    const unsigned short* __restrict__ wop,
                    const float* __restrict__ bo, float* __restrict__ out)
{
    __shared__ unsigned short Ach[64 * 64], Bh[128 * 64];   // 24KB

    const int nbase = blockIdx.x * 128;
    const int mbase = blockIdx.y * 64;

    const int tid  = threadIdx.x;
    const int w    = tid >> 6;
    const int lane = tid & 63;
    const int quad = lane >> 4;
    const int l16  = lane & 15;
    const int wm   = (w >> 1) * 32;
    const int wn   = (w & 1) * 64;

    f32x4 acc[2][4];
#pragma unroll
    for (int i = 0; i < 2; i++)
#pragma unroll
        for (int j = 0; j < 4; j++) acc[i][j] = (f32x4)0.f;

#pragma unroll 1
    for (int kt = 0; kt < KDIM; kt += 64) {
        __syncthreads();
#pragma unroll
        for (int i = 0; i < 2; i++) {
            int u = tid + i * 256;              // 512 chunks for A
            int r = u >> 3, cp = u & 7;
            int c = cp ^ (r & 7);
            gload16(ctxh + (size_t)(mbase + r) * KDIM + kt + c * 8, &Ach[u * 8]);
        }
#pragma unroll
        for (int i = 0; i < 4; i++) {
            int u = tid + i * 256;              // 1024 chunks for B
            int r = u >> 3, cp = u & 7;
            int c = cp ^ (r & 7);
            gload16(wop + (size_t)(nbase + r) * KDIM + kt + c * 8, &Bh[u * 8]);
        }
        __syncthreads();

#pragma unroll
        for (int ks = 0; ks < 2; ks++) {
            f16x8 ah[2], bfr[4];
#pragma unroll
            for (int i = 0; i < 2; i++) {
                int r = wm + i * 16 + l16;
                ah[i] = *(const f16x8*)&Ach[(r * 8 + ((ks * 4 + quad) ^ (r & 7))) * 8];
            }
#pragma unroll
            for (int j = 0; j < 4; j++) {
                int r = wn + j * 16 + l16;
                bfr[j] = *(const f16x8*)&Bh[(r * 8 + ((ks * 4 + quad) ^ (r & 7))) * 8];
            }
#pragma unroll
            for (int i = 0; i < 2; i++)
#pragma unroll
                for (int j = 0; j < 4; j++)
                    acc[i][j] = __builtin_amdgcn_mfma_f32_16x16x32_f16(ah[i], bfr[j], acc[i][j], 0, 0, 0);
        }
    }

#pragma unroll
    for (int j = 0; j < 4; j++) {
        int n = nbase + wn + j * 16 + l16;
        float bj = bo[n];
#pragma unroll
        for (int i = 0; i < 2; i++)
#pragma unroll
            for (int rr = 0; rr < 4; rr++) {
                int m = mbase + wm + i * 16 + quad * 4 + rr;
                out[(size_t)m * EE + n] = acc[i][j][rr] + bj;
            }
    }
}

// ---------------------------------------------------------------------------
// MFMA flash attention, fp16, swapped-operand layout, BM=128 (4 waves x 32
// query rows), XCD-bijective block swizzle. Same as R10 except the epilogue
// writes a SINGLE fp16 ctx plane (no hi/lo split).
// ---------------------------------------------------------------------------
__global__ __launch_bounds__(256)
void attn_kernel(const unsigned short* __restrict__ qp_, const unsigned short* __restrict__ kp_,
                 const unsigned short* __restrict__ vtp_,
                 const float* __restrict__ mask, const int* __restrict__ mflag,
                 unsigned short* __restrict__ ctxh)
{
    __shared__ unsigned short Ks[2][64 * 64];  // rows kv, cols d; chunk-XOR swizzled
    __shared__ unsigned short Vt[2][64 * 64];  // rows d, cols kv; chunk-XOR swizzled

    const int orig = blockIdx.x;
    const int wgid = (orig & 7) * 64 + (orig >> 3);
    const int bh = wgid >> 3;
    const int b  = bh >> 4;
    const int h  = bh & 15;
    const int m0 = (wgid & 7) * 128;
    const size_t hoff = (size_t)bh * TT * DD;
    const unsigned short* qhp = qp_ + hoff;
    const unsigned short* khp = kp_ + hoff;
    const unsigned short* vtp = vtp_ + hoff;   // [D][T] for this bh
    const float* mb = mask + (size_t)b * TT * TT;  // [m][kv] (general path only)

    const int tid  = threadIdx.x;
    const int w    = tid >> 6;
    const int lane = tid & 63;
    const int quad = lane >> 4;
    const int l16  = lane & 15;
    const int mw   = m0 + w * 32;              // wave's 32-row base

    const int usemask = mflag[0];              // wave-uniform scalar

    // ---- loop-invariant LDS element offsets (runtime part only) ----
    const int lm7 = l16 & 7;
    const int x0  = l16 * 64 + ((quad)     ^ lm7) * 8;
    const int x1  = l16 * 64 + ((4 + quad) ^ lm7) * 8;
    const int qh  = quad >> 1, ql = quad & 1;
    int yy[4];
#pragma unroll
    for (int t = 0; t < 4; t++)
        yy[t] = l16 * 64 + ((2 * t + qh) ^ lm7) * 8 + ql * 4;
    const unsigned short* Ksf = &Ks[0][0];
    const unsigned short* Vtf = &Vt[0][0];

    // Q fragments: 2 row-groups, resident whole kernel
    f16x8 qf[2][2];
#pragma unroll
    for (int g = 0; g < 2; g++)
#pragma unroll
        for (int s = 0; s < 2; s++)
            qf[g][s] = *(const f16x8*)(qhp + (size_t)(mw + g * 16 + l16) * DD + s * 32 + quad * 8);

    f32x4 o2[2][4];              // O^T frags per group
#pragma unroll
    for (int g = 0; g < 2; g++)
#pragma unroll
        for (int u = 0; u < 4; u++) o2[g][u] = (f32x4)0.f;
    f32x4 lv[2];
    lv[0] = (f32x4)0.f; lv[1] = (f32x4)0.f;
    const f32x4 zc = (f32x4)0.f;
    f16x4 onesv;
    onesv[0] = (_Float16)1.f; onesv[1] = (_Float16)1.f;
    onesv[2] = (_Float16)1.f; onesv[3] = (_Float16)1.f;
    float m_i[2] = { -INFINITY, -INFINITY };

    // prologue: stage tile 0 (source-side XOR swizzle, linear LDS dest)
#pragma unroll
    for (int i = 0; i < 2; i++) {
        int u = tid + i * 256;
        int r = u >> 3, cp = u & 7;
        int c = cp ^ (r & 7);
        gload16(khp + (size_t)r * DD + c * 8, &Ks[0][u * 8]);
        gload16(vtp + (size_t)r * TT + c * 8, &Vt[0][u * 8]);
    }
    __syncthreads();

#pragma unroll 2
    for (int it = 0; it < 16; ++it) {
        const int n0  = it * 64;
        const int cur = it & 1;              // compile-time per unrolled copy

        // stage NEXT K/V tile into the other buffer; overlaps all compute below
        if (it < 15) {
#pragma unroll
            for (int i = 0; i < 2; i++) {
                int u = tid + i * 256;
                int r = u >> 3, cp = u & 7;
                int c = cp ^ (r & 7);
                gload16(khp + (size_t)(n0 + 64 + r) * DD + c * 8, &Ks[cur ^ 1][u * 8]);
                gload16(vtp + (size_t)r * TT + n0 + 64 + c * 8,   &Vt[cur ^ 1][u * 8]);
            }
        }

        // S^T init: zero C (fast path) or strided mask reads (general path)
        f32x4 st[2][4];
        if (usemask) {
#pragma unroll
            for (int g = 0; g < 2; g++)
#pragma unroll
                for (int t = 0; t < 4; t++)
#pragma unroll
                    for (int r = 0; r < 4; r++)
                        st[g][t][r] = mb[(size_t)(mw + g * 16 + l16) * TT + n0 + 16 * t + quad * 4 + r] * LOG2E;
        } else {
#pragma unroll
            for (int g = 0; g < 2; g++)
#pragma unroll
                for (int t = 0; t < 4; t++) st[g][t] = zc;
        }

        // S^T = K.Q^T + init; each kf feeds BOTH row-groups
        __builtin_amdgcn_s_setprio(1);
#pragma unroll
        for (int t = 0; t < 4; t++) {
            const f16x8 kf = *(const f16x8*)(Ksf + cur * 4096 + x0 + t * 1024);
            st[0][t] = __builtin_amdgcn_mfma_f32_16x16x32_f16(kf, qf[0][0], st[0][t], 0, 0, 0);
            st[1][t] = __builtin_amdgcn_mfma_f32_16x16x32_f16(kf, qf[1][0], st[1][t], 0, 0, 0);
        }
#pragma unroll
        for (int t = 0; t < 4; t++) {
            const f16x8 kf = *(const f16x8*)(Ksf + cur * 4096 + x1 + t * 1024);
            st[0][t] = __builtin_amdgcn_mfma_f32_16x16x32_f16(kf, qf[0][1], st[0][t], 0, 0, 0);
            st[1][t] = __builtin_amdgcn_mfma_f32_16x16x32_f16(kf, qf[1][1], st[1][t], 0, 0, 0);
        }
        __builtin_amdgcn_s_setprio(0);

        // online softmax per row-group
        f16x4 pb[2][4];
#pragma unroll
        for (int g = 0; g < 2; g++) {
            float g0 = mx3(st[g][0][0], st[g][0][1], st[g][0][2]);
            float g1 = mx3(st[g][0][3], st[g][1][0], st[g][1][1]);
            float g2 = mx3(st[g][1][2], st[g][1][3], st[g][2][0]);
            float g3 = mx3(st[g][2][1], st[g][2][2], st[g][2][3]);
            float g4 = mx3(st[g][3][0], st[g][3][1], st[g][3][2]);
            float rm = fmaxf(mx3(g0, g1, g2), mx3(g3, g4, st[g][3][3]));
            rm = fmaxf(rm, __shfl_xor(rm, 16));
            rm = fmaxf(rm, __shfl_xor(rm, 32));

            // defer-max (T13)
            if (__any(rm > m_i[g] + 8.f)) {
                float mn    = fmaxf(m_i[g], rm);
                float alpha = exp2f(m_i[g] - mn);
                m_i[g] = mn;
#pragma unroll
                for (int rr = 0; rr < 4; rr++) lv[g][rr] *= alpha;
#pragma unroll
                for (int u = 0; u < 4; u++)
#pragma unroll
                    for (int rr = 0; rr < 4; rr++) o2[g][u][rr] *= alpha;
            }

            // P = exp2(S - m), packed fp16 (B-frag of 16x16x16 directly)
#pragma unroll
            for (int t = 0; t < 4; t++) {
                float p0 = exp2f(st[g][t][0] - m_i[g]);
                float p1 = exp2f(st[g][t][1] - m_i[g]);
                float p2 = exp2f(st[g][t][2] - m_i[g]);
                float p3 = exp2f(st[g][t][3] - m_i[g]);
                f16x2 plo = cvt_pk(p0, p1);
                f16x2 phi = cvt_pk(p2, p3);
                f16x4 pv;
                pv[0] = plo[0]; pv[1] = plo[1]; pv[2] = phi[0]; pv[3] = phi[1];
                pb[g][t] = pv;
            }
        }

        // l += sum_k P (ones-MFMA); O^T += V^T.P^T; each vv feeds BOTH groups
        __builtin_amdgcn_s_setprio(1);
#pragma unroll
        for (int t = 0; t < 4; t++) {
            lv[0] = __builtin_amdgcn_mfma_f32_16x16x16f16(onesv, pb[0][t], lv[0], 0, 0, 0);
            lv[1] = __builtin_amdgcn_mfma_f32_16x16x16f16(onesv, pb[1][t], lv[1], 0, 0, 0);
        }
#pragma unroll
        for (int u = 0; u < 4; u++) {
#pragma unroll
            for (int t = 0; t < 4; t++) {
                const f16x4 vv = *(const f16x4*)(Vtf + cur * 4096 + yy[t] + u * 1024);
                o2[0][u] = __builtin_amdgcn_mfma_f32_16x16x16f16(vv, pb[0][t], o2[0][u], 0, 0, 0);
                o2[1][u] = __builtin_amdgcn_mfma_f32_16x16x16f16(vv, pb[1][t], o2[1][u], 0, 0, 0);
            }
        }
        __builtin_amdgcn_s_setprio(0);

        // single barrier per iteration
        __syncthreads();
    }

    // epilogue: normalize, single fp16 ctx plane [B,T,E]
#pragma unroll
    for (int g = 0; g < 2; g++) {
        float inv = 1.0f / lv[g][0];
        int m = mw + g * 16 + l16;
#pragma unroll
        for (int u = 0; u < 4; u++)
#pragma unroll
            for (int rr = 0; rr < 4; rr++) {
                size_t off = ((size_t)(b * TT + m)) * EE + h * DD + u * 16 + quad * 4 + rr;
                ctxh[off] = f2h(o2[g][u][rr] * inv);
            }
    }
}

// ---------------------------------------------------------------------------
extern "C" void kernel_launch(void* const* d_in, const int* in_sizes, int n_in,
                              void* d_out, int out_size, void* d_ws, size_t ws_size,
                              hipStream_t stream)
{
    const float* hs   = (const float*)d_in[0];
    const float* mask = (const float*)d_in[1];
    const float* Wq   = (const float*)d_in[2];
    const float* bq   = (const float*)d_in[3];
    const float* Wk   = (const float*)d_in[4];
    const float* bk   = (const float*)d_in[5];
    const float* Wv   = (const float*)d_in[6];
    const float* bv   = (const float*)d_in[7];
    const float* Wo   = (const float*)d_in[8];
    const float* bo   = (const float*)d_in[9];
    float* out = (float*)d_out;

    unsigned short* ws   = (unsigned short*)d_ws;
    unsigned short* hsp  = ws;                                  // fp16 hs (-> ctx)
    unsigned short* wqp  = ws + (size_t)N_HS;                   // wq,wk,wv,wo
    unsigned short* wop  = wqp + 3 * (size_t)N_W;
    unsigned short* qkvb = wqp + 4 * (size_t)N_W;               // q,k,v planes
    unsigned short* qp   = qkvb;
    unsigned short* kp   = qp + (size_t)NQKV;
    unsigned short* vp   = kp + (size_t)NQKV;
    unsigned short* ctxh = ws;                                  // alias hs (dead after qkv)
    unsigned short* vtp  = qkvb + 3 * (size_t)NQKV + (size_t)N_HS;  // V^T [B,H,D,T]
    int*            mflag = (int*)(vtp + (size_t)NQKV);         // zero-mask flag

    (void)hipMemsetAsync(mflag, 0, sizeof(int), stream);
    split_kernel<<<12288, 256, 0, stream>>>(hs, Wq, Wk, Wv, Wo, mask, mflag, ws);
    qkv_kernel<<<dim3(24, 32), 256, 0, stream>>>(hsp, wqp, bq, bk, bv, qkvb);
    vtrans_kernel<<<dim3(TT / 64, BB * HH), 256, 0, stream>>>(vp, vtp);
    attn_kernel<<<512, 256, 0, stream>>>(qp, kp, vtp, mask, mflag, ctxh);
    outproj_kernel<<<dim3(8, 64), 256, 0, stream>>>(ctxh, wop, bo, out);
}

// Round 13
// 205.562 us; speedup vs baseline: 1.0674x; 1.0177x over previous
//
#include <hip/hip_runtime.h>
#include <math.h>

// Problem constants
#define BB 4
#define TT 1024
#define EE 1024
#define HH 16
#define DD 64
#define KDIM 1024
#define N_HS (4096 * 1024)     // hidden_states elems (also ctx)
#define N_W  (1024 * 1024)     // one weight matrix elems
#define NQKV (BB * HH * TT * DD)
#define LOG2E 1.44269504088896340736f

typedef _Float16 f16x8 __attribute__((ext_vector_type(8)));   // 4 VGPRs
typedef _Float16 f16x4 __attribute__((ext_vector_type(4)));   // 2 VGPRs
typedef _Float16 f16x2 __attribute__((ext_vector_type(2)));   // 1 VGPR
typedef float    f32x4 __attribute__((ext_vector_type(4)));

// fp32 -> fp16 bits, RTNE
__device__ __forceinline__ unsigned short f2h(float x) {
    _Float16 h = (_Float16)x;
    return __builtin_bit_cast(unsigned short, h);
}

// packed fp32x2 -> fp16x2 (RTZ)
__device__ __forceinline__ f16x2 cvt_pk(float a, float b) {
    return __builtin_bit_cast(f16x2, __builtin_amdgcn_cvt_pkrtz(a, b));
}

// async global->LDS 16B copy
__device__ __forceinline__ void gload16(const void* g, void* l) {
    __builtin_amdgcn_global_load_lds(
        (const __attribute__((address_space(1))) void*)g,
        (__attribute__((address_space(3))) void*)l, 16, 0, 0);
}

__device__ __forceinline__ float mx3(float a, float b, float c) {
    return fmaxf(fmaxf(a, b), c);   // clang fuses to v_max3_f32
}

// ---------------------------------------------------------------------------
// Elementwise fp32 -> fp16 convert: hs + 4 weights, single plane each.
// Block 0 also zeroes mflag (no reader within this dispatch; stream order
// protects the qkv-scan writers and attn reader). The mask zero-scan itself
// now lives in qkv_kernel's grid where it overlaps the GEMM blocks.
// ws layout (ushort units):
//   [0]                      hs (N_HS)            (aliased as ctx later)
//   [N_HS]                   wq, wk, wv, wo       (N_W each)
//   [N_HS+4*N_W]             q, k, v              (NQKV each)
//   [N_HS+4*N_W+3*NQKV]      (spare)              (N_HS)
//   [.. + N_HS]              vT                   (NQKV, [B,H,D,T])
//   [.. + NQKV]              mflag (int)
// ---------------------------------------------------------------------------
__global__ __launch_bounds__(256)
void split_kernel(const float* __restrict__ hs,
                  const float* __restrict__ Wq, const float* __restrict__ Wk,
                  const float* __restrict__ Wv, const float* __restrict__ Wo,
                  int* __restrict__ mflag,
                  unsigned short* __restrict__ ws)
{
    if (blockIdx.x == 0 && threadIdx.x == 0) mflag[0] = 0;
    const int u = blockIdx.x * 256 + threadIdx.x;   // float4 id, 2,097,152 total
    const float* src;
    unsigned short* dst;
    if (u < (N_HS / 4)) {
        src = hs + (size_t)u * 4;
        dst = ws + (size_t)u * 4;
    } else {
        int v = u - N_HS / 4;
        int wsel = v >> 18;             // N_W/4 = 262144 float4 per weight
        int wo   = v & 0x3FFFF;
        const float* Wsrc = (wsel == 0) ? Wq : (wsel == 1) ? Wk : (wsel == 2) ? Wv : Wo;
        src = Wsrc + (size_t)wo * 4;
        dst = ws + (size_t)N_HS + (size_t)wsel * N_W + (size_t)wo * 4;
    }
    float4 x = *(const float4*)src;
    ushort4 h4;
    h4.x = f2h(x.x); h4.y = f2h(x.y); h4.z = f2h(x.z); h4.w = f2h(x.w);
    *(ushort4*)dst = h4;
}

// ---------------------------------------------------------------------------
// QKV projection, single-fp16 MFMA, BK=64 single-buffered (R9 structure).
// Q additionally scaled by log2e so the attention softmax uses exp2.
// Grid x: [0,24) = GEMM blocks (widx*8+nbase), [24,32) = mask zero-scan
// blocks (256 of them, overlapping the GEMM for free).
// ---------------------------------------------------------------------------
__global__ __launch_bounds__(256)
void qkv_kernel(const unsigned short* __restrict__ hsp,
                const unsigned short* __restrict__ wqp,
                const float* __restrict__ bq, const float* __restrict__ bk,
                const float* __restrict__ bv,
                const float* __restrict__ mask, int* __restrict__ mflag,
                unsigned short* __restrict__ qkvb)
{
    __shared__ unsigned short Ah[128 * 64], Bh[128 * 64];   // 32KB total

    if (blockIdx.x >= 24) {
        // mask scan: 256 blocks x 256 threads x 16 float4 = 1,048,576 float4
        const int sid = (blockIdx.x - 24) * 32 + blockIdx.y;
        const int tid = threadIdx.x;
        bool nz = false;
#pragma unroll
        for (int i = 0; i < 16; i++) {
            size_t idx = ((size_t)sid * 16 + i) * 256 + tid;
            float4 x = *(const float4*)(mask + idx * 4);
            nz = nz || (x.x != 0.f) || (x.y != 0.f) || (x.z != 0.f) || (x.w != 0.f);
        }
        if (__any(nz) && (tid & 63) == 0)
            atomicOr(mflag, 1);
        return;
    }

    const int widx  = blockIdx.x >> 3;
    const int nbase = (blockIdx.x & 7) * 128;
    const int mbase = blockIdx.y * 128;
    const unsigned short* Wp = wqp + (size_t)widx * N_W;
    const float* bias = (widx == 0) ? bq : (widx == 1) ? bk : bv;
    unsigned short* dst = qkvb + (size_t)widx * NQKV;
    const float scale = (widx == 0) ? 0.125f * LOG2E : 1.0f;   // D^-0.5 * log2e

    const int tid  = threadIdx.x;
    const int w    = tid >> 6;
    const int lane = tid & 63;
    const int quad = lane >> 4;
    const int l16  = lane & 15;
    const int wm   = (w >> 1) * 64;
    const int wn   = (w & 1) * 64;

    f32x4 acc[4][4];
#pragma unroll
    for (int i = 0; i < 4; i++)
#pragma unroll
        for (int j = 0; j < 4; j++) acc[i][j] = (f32x4)0.f;

#pragma unroll 1
    for (int kt = 0; kt < KDIM; kt += 64) {
        __syncthreads();
#pragma unroll
        for (int i = 0; i < 4; i++) {
            int u = tid + i * 256;              // 16B chunk id, 1024/plane
            int r = u >> 3, cp = u & 7;
            int c = cp ^ (r & 7);
            gload16(hsp + (size_t)(mbase + r) * KDIM + kt + c * 8, &Ah[u * 8]);
            gload16(Wp  + (size_t)(nbase + r) * KDIM + kt + c * 8, &Bh[u * 8]);
        }
        __syncthreads();

#pragma unroll
        for (int ks = 0; ks < 2; ks++) {
            f16x8 af[4], bfr[4];
#pragma unroll
            for (int i = 0; i < 4; i++) {
                int r = wm + i * 16 + l16;
                af[i] = *(const f16x8*)&Ah[(r * 8 + ((ks * 4 + quad) ^ (r & 7))) * 8];
            }
#pragma unroll
            for (int j = 0; j < 4; j++) {
                int r = wn + j * 16 + l16;
                bfr[j] = *(const f16x8*)&Bh[(r * 8 + ((ks * 4 + quad) ^ (r & 7))) * 8];
            }
#pragma unroll
            for (int i = 0; i < 4; i++)
#pragma unroll
                for (int j = 0; j < 4; j++)
                    acc[i][j] = __builtin_amdgcn_mfma_f32_16x16x32_f16(af[i], bfr[j], acc[i][j], 0, 0, 0);
        }
    }

    // epilogue: +bias, *scale, fp16, scatter to [B,H,T,D]
#pragma unroll
    for (int j = 0; j < 4; j++) {
        int n = nbase + wn + j * 16 + l16;
        int h = n >> 6, d = n & 63;
        float bj = bias[n];
#pragma unroll
        for (int i = 0; i < 4; i++)
#pragma unroll
            for (int rr = 0; rr < 4; rr++) {
                int m = mbase + wm + i * 16 + quad * 4 + rr;
                int b = m >> 10, t = m & 1023;
                dst[(((size_t)(b * HH + h) * TT + t) * DD + d)] =
                    f2h((acc[i][j][rr] + bj) * scale);
            }
    }
}

// ---------------------------------------------------------------------------
// V transpose: [B,H,T,D] -> [B,H,D,T] fp16, via LDS tile.
// ---------------------------------------------------------------------------
__global__ __launch_bounds__(256)
void vtrans_kernel(const unsigned short* __restrict__ vp,
                   unsigned short* __restrict__ vtp)
{
    __shared__ unsigned short Ts[64 * 72];
    const int bh = blockIdx.y;
    const int t0 = blockIdx.x * 64;
    const unsigned short* src = vp  + (size_t)bh * TT * DD + (size_t)t0 * DD;
    unsigned short*       dst = vtp + (size_t)bh * DD * TT + t0;
    const int tid = threadIdx.x;

#pragma unroll
    for (int i = 0; i < 2; i++) {
        int id = tid + i * 256;           // 512 uint4: row r (token), chunk c (8 d)
        int r = id >> 3, c = id & 7;
        *(uint4*)&Ts[r * 72 + c * 8] = *(const uint4*)(src + (size_t)r * DD + c * 8);
    }
    __syncthreads();
#pragma unroll
    for (int i = 0; i < 2; i++) {
        int id = tid + i * 256;           // 512 uint4: row d, chunk c (8 tokens)
        int d = id >> 3, c = id & 7;
        unsigned short tmp[8];
#pragma unroll
        for (int j = 0; j < 8; j++) tmp[j] = Ts[(c * 8 + j) * 72 + d];
        uint4 o;
        o.x = (unsigned int)tmp[0] | ((unsigned int)tmp[1] << 16);
        o.y = (unsigned int)tmp[2] | ((unsigned int)tmp[3] << 16);
        o.z = (unsigned int)tmp[4] | ((unsigned int)tmp[5] << 16);
        o.w = (unsigned int)tmp[6] | ((unsigned int)tmp[7] << 16);
        *(uint4*)(dst + (size_t)d * TT + c * 8) = o;
    }
}

// ---------------------------------------------------------------------------
// Out projection, SINGLE-term fp16, BK=64.
// ---------------------------------------------------------------------------
__global__ __launch_bounds__(256)
void outproj_kernel(const unsigned short* __restrict__ ctxh,
                    const unsigned short* __restrict__ wop,
                    const float* __restrict__ bo, float* __restrict__ out)
{
    __shared__ unsigned short Ach[64 * 64], Bh[128 * 64];   // 24KB

    const int nbase = blockIdx.x * 128;
    const int mbase = blockIdx.y * 64;

    const int tid  = threadIdx.x;
    const int w    = tid >> 6;
    const int lane = tid & 63;
    const int quad = lane >> 4;
    const int l16  = lane & 15;
    const int wm   = (w >> 1) * 32;
    const int wn   = (w & 1) * 64;

    f32x4 acc[2][4];
#pragma unroll
    for (int i = 0; i < 2; i++)
#pragma unroll
        for (int j = 0; j < 4; j++) acc[i][j] = (f32x4)0.f;

#pragma unroll 1
    for (int kt = 0; kt < KDIM; kt += 64) {
        __syncthreads();
#pragma unroll
        for (int i = 0; i < 2; i++) {
            int u = tid + i * 256;              // 512 chunks for A
            int r = u >> 3, cp = u & 7;
            int c = cp ^ (r & 7);
            gload16(ctxh + (size_t)(mbase + r) * KDIM + kt + c * 8, &Ach[u * 8]);
        }
#pragma unroll
        for (int i = 0; i < 4; i++) {
            int u = tid + i * 256;              // 1024 chunks for B
            int r = u >> 3, cp = u & 7;
            int c = cp ^ (r & 7);
            gload16(wop + (size_t)(nbase + r) * KDIM + kt + c * 8, &Bh[u * 8]);
        }
        __syncthreads();

#pragma unroll
        for (int ks = 0; ks < 2; ks++) {
            f16x8 ah[2], bfr[4];
#pragma unroll
            for (int i = 0; i < 2; i++) {
                int r = wm + i * 16 + l16;
                ah[i] = *(const f16x8*)&Ach[(r * 8 + ((ks * 4 + quad) ^ (r & 7))) * 8];
            }
#pragma unroll
            for (int j = 0; j < 4; j++) {
                int r = wn + j * 16 + l16;
                bfr[j] = *(const f16x8*)&Bh[(r * 8 + ((ks * 4 + quad) ^ (r & 7))) * 8];
            }
#pragma unroll
            for (int i = 0; i < 2; i++)
#pragma unroll
                for (int j = 0; j < 4; j++)
                    acc[i][j] = __builtin_amdgcn_mfma_f32_16x16x32_f16(ah[i], bfr[j], acc[i][j], 0, 0, 0);
        }
    }

#pragma unroll
    for (int j = 0; j < 4; j++) {
        int n = nbase + wn + j * 16 + l16;
        float bj = bo[n];
#pragma unroll
        for (int i = 0; i < 2; i++)
#pragma unroll
            for (int rr = 0; rr < 4; rr++) {
                int m = mbase + wm + i * 16 + quad * 4 + rr;
                out[(size_t)m * EE + n] = acc[i][j][rr] + bj;
            }
    }
}

// ---------------------------------------------------------------------------
// MFMA flash attention, fp16, swapped-operand layout, BM=128 (4 waves x 32
// query rows), XCD-bijective block swizzle. Unchanged from R12.
// ---------------------------------------------------------------------------
__global__ __launch_bounds__(256)
void attn_kernel(const unsigned short* __restrict__ qp_, const unsigned short* __restrict__ kp_,
                 const unsigned short* __restrict__ vtp_,
                 const float* __restrict__ mask, const int* __restrict__ mflag,
                 unsigned short* __restrict__ ctxh)
{
    __shared__ unsigned short Ks[2][64 * 64];  // rows kv, cols d; chunk-XOR swizzled
    __shared__ unsigned short Vt[2][64 * 64];  // rows d, cols kv; chunk-XOR swizzled

    const int orig = blockIdx.x;
    const int wgid = (orig & 7) * 64 + (orig >> 3);
    const int bh = wgid >> 3;
    const int b  = bh >> 4;
    const int h  = bh & 15;
    const int m0 = (wgid & 7) * 128;
    const size_t hoff = (size_t)bh * TT * DD;
    const unsigned short* qhp = qp_ + hoff;
    const unsigned short* khp = kp_ + hoff;
    const unsigned short* vtp = vtp_ + hoff;   // [D][T] for this bh
    const float* mb = mask + (size_t)b * TT * TT;  // [m][kv] (general path only)

    const int tid  = threadIdx.x;
    const int w    = tid >> 6;
    const int lane = tid & 63;
    const int quad = lane >> 4;
    const int l16  = lane & 15;
    const int mw   = m0 + w * 32;              // wave's 32-row base

    const int usemask = mflag[0];              // wave-uniform scalar

    // ---- loop-invariant LDS element offsets (runtime part only) ----
    const int lm7 = l16 & 7;
    const int x0  = l16 * 64 + ((quad)     ^ lm7) * 8;
    const int x1  = l16 * 64 + ((4 + quad) ^ lm7) * 8;
    const int qh  = quad >> 1, ql = quad & 1;
    int yy[4];
#pragma unroll
    for (int t = 0; t < 4; t++)
        yy[t] = l16 * 64 + ((2 * t + qh) ^ lm7) * 8 + ql * 4;
    const unsigned short* Ksf = &Ks[0][0];
    const unsigned short* Vtf = &Vt[0][0];

    // Q fragments: 2 row-groups, resident whole kernel
    f16x8 qf[2][2];
#pragma unroll
    for (int g = 0; g < 2; g++)
#pragma unroll
        for (int s = 0; s < 2; s++)
            qf[g][s] = *(const f16x8*)(qhp + (size_t)(mw + g * 16 + l16) * DD + s * 32 + quad * 8);

    f32x4 o2[2][4];              // O^T frags per group
#pragma unroll
    for (int g = 0; g < 2; g++)
#pragma unroll
        for (int u = 0; u < 4; u++) o2[g][u] = (f32x4)0.f;
    f32x4 lv[2];
    lv[0] = (f32x4)0.f; lv[1] = (f32x4)0.f;
    const f32x4 zc = (f32x4)0.f;
    f16x4 onesv;
    onesv[0] = (_Float16)1.f; onesv[1] = (_Float16)1.f;
    onesv[2] = (_Float16)1.f; onesv[3] = (_Float16)1.f;
    float m_i[2] = { -INFINITY, -INFINITY };

    // prologue: stage tile 0 (source-side XOR swizzle, linear LDS dest)
#pragma unroll
    for (int i = 0; i < 2; i++) {
        int u = tid + i * 256;
        int r = u >> 3, cp = u & 7;
        int c = cp ^ (r & 7);
        gload16(khp + (size_t)r * DD + c * 8, &Ks[0][u * 8]);
        gload16(vtp + (size_t)r * TT + c * 8, &Vt[0][u * 8]);
    }
    __syncthreads();

#pragma unroll 2
    for (int it = 0; it < 16; ++it) {
        const int n0  = it * 64;
        const int cur = it & 1;              // compile-time per unrolled copy

        // stage NEXT K/V tile into the other buffer; overlaps all compute below
        if (it < 15) {
#pragma unroll
            for (int i = 0; i < 2; i++) {
                int u = tid + i * 256;
                int r = u >> 3, cp = u & 7;
                int c = cp ^ (r & 7);
                gload16(khp + (size_t)(n0 + 64 + r) * DD + c * 8, &Ks[cur ^ 1][u * 8]);
                gload16(vtp + (size_t)r * TT + n0 + 64 + c * 8,   &Vt[cur ^ 1][u * 8]);
            }
        }

        // S^T init: zero C (fast path) or strided mask reads (general path)
        f32x4 st[2][4];
        if (usemask) {
#pragma unroll
            for (int g = 0; g < 2; g++)
#pragma unroll
                for (int t = 0; t < 4; t++)
#pragma unroll
                    for (int r = 0; r < 4; r++)
                        st[g][t][r] = mb[(size_t)(mw + g * 16 + l16) * TT + n0 + 16 * t + quad * 4 + r] * LOG2E;
        } else {
#pragma unroll
            for (int g = 0; g < 2; g++)
#pragma unroll
                for (int t = 0; t < 4; t++) st[g][t] = zc;
        }

        // S^T = K.Q^T + init; each kf feeds BOTH row-groups
        __builtin_amdgcn_s_setprio(1);
#pragma unroll
        for (int t = 0; t < 4; t++) {
            const f16x8 kf = *(const f16x8*)(Ksf + cur * 4096 + x0 + t * 1024);
            st[0][t] = __builtin_amdgcn_mfma_f32_16x16x32_f16(kf, qf[0][0], st[0][t], 0, 0, 0);
            st[1][t] = __builtin_amdgcn_mfma_f32_16x16x32_f16(kf, qf[1][0], st[1][t], 0, 0, 0);
        }
#pragma unroll
        for (int t = 0; t < 4; t++) {
            const f16x8 kf = *(const f16x8*)(Ksf + cur * 4096 + x1 + t * 1024);
            st[0][t] = __builtin_amdgcn_mfma_f32_16x16x32_f16(kf, qf[0][1], st[0][t], 0, 0, 0);
            st[1][t] = __builtin_amdgcn_mfma_f32_16x16x32_f16(kf, qf[1][1], st[1][t], 0, 0, 0);
        }
        __builtin_amdgcn_s_setprio(0);

        // online softmax per row-group
        f16x4 pb[2][4];
#pragma unroll
        for (int g = 0; g < 2; g++) {
            float g0 = mx3(st[g][0][0], st[g][0][1], st[g][0][2]);
            float g1 = mx3(st[g][0][3], st[g][1][0], st[g][1][1]);
            float g2 = mx3(st[g][1][2], st[g][1][3], st[g][2][0]);
            float g3 = mx3(st[g][2][1], st[g][2][2], st[g][2][3]);
            float g4 = mx3(st[g][3][0], st[g][3][1], st[g][3][2]);
            float rm = fmaxf(mx3(g0, g1, g2), mx3(g3, g4, st[g][3][3]));
            rm = fmaxf(rm, __shfl_xor(rm, 16));
            rm = fmaxf(rm, __shfl_xor(rm, 32));

            // defer-max (T13)
            if (__any(rm > m_i[g] + 8.f)) {
                float mn    = fmaxf(m_i[g], rm);
                float alpha = exp2f(m_i[g] - mn);
                m_i[g] = mn;
#pragma unroll
                for (int rr = 0; rr < 4; rr++) lv[g][rr] *= alpha;
#pragma unroll
                for (int u = 0; u < 4; u++)
#pragma unroll
                    for (int rr = 0; rr < 4; rr++) o2[g][u][rr] *= alpha;
            }

            // P = exp2(S - m), packed fp16 (B-frag of 16x16x16 directly)
#pragma unroll
            for (int t = 0; t < 4; t++) {
                float p0 = exp2f(st[g][t][0] - m_i[g]);
                float p1 = exp2f(st[g][t][1] - m_i[g]);
                float p2 = exp2f(st[g][t][2] - m_i[g]);
                float p3 = exp2f(st[g][t][3] - m_i[g]);
                f16x2 plo = cvt_pk(p0, p1);
                f16x2 phi = cvt_pk(p2, p3);
                f16x4 pv;
                pv[0] = plo[0]; pv[1] = plo[1]; pv[2] = phi[0]; pv[3] = phi[1];
                pb[g][t] = pv;
            }
        }

        // l += sum_k P (ones-MFMA); O^T += V^T.P^T; each vv feeds BOTH groups
        __builtin_amdgcn_s_setprio(1);
#pragma unroll
        for (int t = 0; t < 4; t++) {
            lv[0] = __builtin_amdgcn_mfma_f32_16x16x16f16(onesv, pb[0][t], lv[0], 0, 0, 0);
            lv[1] = __builtin_amdgcn_mfma_f32_16x16x16f16(onesv, pb[1][t], lv[1], 0, 0, 0);
        }
#pragma unroll
        for (int u = 0; u < 4; u++) {
#pragma unroll
            for (int t = 0; t < 4; t++) {
                const f16x4 vv = *(const f16x4*)(Vtf + cur * 4096 + yy[t] + u * 1024);
                o2[0][u] = __builtin_amdgcn_mfma_f32_16x16x16f16(vv, pb[0][t], o2[0][u], 0, 0, 0);
                o2[1][u] = __builtin_amdgcn_mfma_f32_16x16x16f16(vv, pb[1][t], o2[1][u], 0, 0, 0);
            }
        }
        __builtin_amdgcn_s_setprio(0);

        // single barrier per iteration
        __syncthreads();
    }

    // epilogue: normalize, single fp16 ctx plane [B,T,E]
#pragma unroll
    for (int g = 0; g < 2; g++) {
        float inv = 1.0f / lv[g][0];
        int m = mw + g * 16 + l16;
#pragma unroll
        for (int u = 0; u < 4; u++)
#pragma unroll
            for (int rr = 0; rr < 4; rr++) {
                size_t off = ((size_t)(b * TT + m)) * EE + h * DD + u * 16 + quad * 4 + rr;
                ctxh[off] = f2h(o2[g][u][rr] * inv);
            }
    }
}

// ---------------------------------------------------------------------------
extern "C" void kernel_launch(void* const* d_in, const int* in_sizes, int n_in,
                              void* d_out, int out_size, void* d_ws, size_t ws_size,
                              hipStream_t stream)
{
    const float* hs   = (const float*)d_in[0];
    const float* mask = (const float*)d_in[1];
    const float* Wq   = (const float*)d_in[2];
    const float* bq   = (const float*)d_in[3];
    const float* Wk   = (const float*)d_in[4];
    const float* bk   = (const float*)d_in[5];
    const float* Wv   = (const float*)d_in[6];
    const float* bv   = (const float*)d_in[7];
    const float* Wo   = (const float*)d_in[8];
    const float* bo   = (const float*)d_in[9];
    float* out = (float*)d_out;

    unsigned short* ws   = (unsigned short*)d_ws;
    unsigned short* hsp  = ws;                                  // fp16 hs (-> ctx)
    unsigned short* wqp  = ws + (size_t)N_HS;                   // wq,wk,wv,wo
    unsigned short* wop  = wqp + 3 * (size_t)N_W;
    unsigned short* qkvb = wqp + 4 * (size_t)N_W;               // q,k,v planes
    unsigned short* qp   = qkvb;
    unsigned short* kp   = qp + (size_t)NQKV;
    unsigned short* vp   = kp + (size_t)NQKV;
    unsigned short* ctxh = ws;                                  // alias hs (dead after qkv)
    unsigned short* vtp  = qkvb + 3 * (size_t)NQKV + (size_t)N_HS;  // V^T [B,H,D,T]
    int*            mflag = (int*)(vtp + (size_t)NQKV);         // zero-mask flag

    split_kernel<<<8192, 256, 0, stream>>>(hs, Wq, Wk, Wv, Wo, mflag, ws);
    qkv_kernel<<<dim3(32, 32), 256, 0, stream>>>(hsp, wqp, bq, bk, bv, mask, mflag, qkvb);
    vtrans_kernel<<<dim3(TT / 64, BB * HH), 256, 0, stream>>>(vp, vtp);
    attn_kernel<<<512, 256, 0, stream>>>(qp, kp, vtp, mask, mflag, ctxh);
    outproj_kernel<<<dim3(8, 64), 256, 0, stream>>>(ctxh, wop, bo, out);
}